// Round 1
// baseline (11508.884 us; speedup 1.0000x reference)
//
#include <hip/hip_runtime.h>

#define NN 100000
#define NE 1600000
#define DIM 128
#define NS 15000

// ---------------- degree / normalization ----------------
__global__ __launch_bounds__(256) void deg_init_k(float* deg) {
    int i = blockIdx.x * 256 + threadIdx.x;
    if (i < NN) deg[i] = 1.0f;  // self-loop
}

__global__ __launch_bounds__(256) void deg_count_k(const int* __restrict__ dst, float* deg) {
    int e = blockIdx.x * 256 + threadIdx.x;
    if (e < NE) atomicAdd(&deg[dst[e]], 1.0f);
}

__global__ __launch_bounds__(256) void dinv_k(float* deg) {
    int i = blockIdx.x * 256 + threadIdx.x;
    if (i < NN) deg[i] = rsqrtf(deg[i]);
}

// ---------------- dense transform: H = X @ W  (X:[N,128], W:[128,128]) ----------------
// block = 256 threads, 32 rows/block. X tile staged in LDS (16 KB); W read from
// global (coalesced across cols, L1/L2 resident: 64 KB).
__global__ __launch_bounds__(256) void gemm_k(const float* __restrict__ X,
                                              const float* __restrict__ W,
                                              float* __restrict__ H) {
    __shared__ float xs[32 * DIM];
    const int tid = threadIdx.x;
    const long long row0 = (long long)blockIdx.x * 32;

    const float4* X4 = (const float4*)(X + row0 * DIM);
    float4* xs4 = (float4*)xs;
#pragma unroll
    for (int i = 0; i < 4; i++) xs4[tid + i * 256] = X4[tid + i * 256];
    __syncthreads();

    const int c = tid & 127;
    const int rbase = (tid >> 7) * 16;  // 0 or 16

    float acc[16];
#pragma unroll
    for (int r = 0; r < 16; r++) acc[r] = 0.f;

    for (int k = 0; k < DIM; k += 4) {
        const float w0 = W[(k + 0) * DIM + c];
        const float w1 = W[(k + 1) * DIM + c];
        const float w2 = W[(k + 2) * DIM + c];
        const float w3 = W[(k + 3) * DIM + c];
#pragma unroll
        for (int r = 0; r < 16; r++) {
            const float4 xv = *(const float4*)&xs[(rbase + r) * DIM + k];
            acc[r] += xv.x * w0 + xv.y * w1 + xv.z * w2 + xv.w * w3;
        }
    }
#pragma unroll
    for (int r = 0; r < 16; r++)
        H[(row0 + rbase + r) * DIM + c] = acc[r];
}

// ---------------- agg = dinv^2 * h  (self-loop message, also zero-inits agg) ----------------
__global__ __launch_bounds__(256) void agg_init_k(const float* __restrict__ dinv,
                                                  const float* __restrict__ H,
                                                  float* __restrict__ agg) {
    long long i = (long long)blockIdx.x * 256 + threadIdx.x;  // over NN*32 float4s
    if (i >= (long long)NN * 32) return;
    const int node = (int)(i >> 5);
    const float d = dinv[node];
    const float s = d * d;
    float4 h = ((const float4*)H)[i];
    float4 o;
    o.x = s * h.x; o.y = s * h.y; o.z = s * h.z; o.w = s * h.w;
    ((float4*)agg)[i] = o;
}

// ---------------- edge scatter: agg[dst] += dinv[src]*dinv[dst]*h[src] ----------------
// 32 threads per edge, each does one float4 slice (4 scalar f32 atomics).
__global__ __launch_bounds__(256) void scatter_k(const int* __restrict__ src,
                                                 const int* __restrict__ dst,
                                                 const float* __restrict__ dinv,
                                                 const float* __restrict__ H,
                                                 float* __restrict__ agg) {
    long long gid = (long long)blockIdx.x * 256 + threadIdx.x;
    const int e = (int)(gid >> 5);
    if (e >= NE) return;
    const int q = (int)(gid & 31);
    const int s = src[e];
    const int t = dst[e];
    const float nrm = dinv[s] * dinv[t];
    const float4 h = ((const float4*)H)[(long long)s * 32 + q];
    float* a = agg + (long long)t * DIM + q * 4;
    atomicAdd(a + 0, nrm * h.x);
    atomicAdd(a + 1, nrm * h.y);
    atomicAdd(a + 2, nrm * h.z);
    atomicAdd(a + 3, nrm * h.w);
}

// ---------------- x = relu(agg + h) ----------------
__global__ __launch_bounds__(256) void relu_k(const float* __restrict__ agg,
                                              const float* __restrict__ H,
                                              float* __restrict__ out) {
    long long i = (long long)blockIdx.x * 256 + threadIdx.x;
    if (i >= (long long)NN * 32) return;
    float4 a = ((const float4*)agg)[i];
    float4 h = ((const float4*)H)[i];
    float4 o;
    o.x = fmaxf(a.x + h.x, 0.f);
    o.y = fmaxf(a.y + h.y, 0.f);
    o.z = fmaxf(a.z + h.z, 0.f);
    o.w = fmaxf(a.w + h.w, 0.f);
    ((float4*)out)[i] = o;
}

// ---------------- seed gather ----------------
__global__ __launch_bounds__(256) void gather_k(const int* __restrict__ seeds,
                                                const float* __restrict__ ent,
                                                float* __restrict__ out) {
    long long gid = (long long)blockIdx.x * 256 + threadIdx.x;
    const int s = (int)(gid >> 5);
    if (s >= NS) return;
    const int q = (int)(gid & 31);
    ((float4*)out)[(long long)s * 32 + q] =
        ((const float4*)ent)[(long long)seeds[s] * 32 + q];
}

// ---------------- per-graph driver (host) ----------------
static void run_graph(const int* edges, const float* emb, const float* W0, const float* W1,
                      float* dinv, float* h, float* agg, float* ent_out, hipStream_t stream) {
    const int* src = edges;       // edges[0,:]
    const int* dst = edges + NE;  // edges[1,:]

    const int gN = (NN + 255) / 256;           // 391
    const int gE = (NE + 255) / 256;           // 6250
    const int gGemm = NN / 32;                 // 3125 (100000 % 32 == 0)
    const int gElem = (NN * 32 + 255) / 256;   // 12500
    const int gScat = (int)(((long long)NE * 32 + 255) / 256);  // 200000

    deg_init_k<<<gN, 256, 0, stream>>>(dinv);
    deg_count_k<<<gE, 256, 0, stream>>>(dst, dinv);
    dinv_k<<<gN, 256, 0, stream>>>(dinv);

    // layer 1: x = emb
    gemm_k<<<gGemm, 256, 0, stream>>>(emb, W0, h);
    agg_init_k<<<gElem, 256, 0, stream>>>(dinv, h, agg);
    scatter_k<<<gScat, 256, 0, stream>>>(src, dst, dinv, h, agg);
    relu_k<<<gElem, 256, 0, stream>>>(agg, h, agg);  // x1 lives in agg

    // layer 2: x = x1 (in agg)
    gemm_k<<<gGemm, 256, 0, stream>>>(agg, W1, h);   // reads x1, writes h
    agg_init_k<<<gElem, 256, 0, stream>>>(dinv, h, agg);  // x1 dead now; overwrite
    scatter_k<<<gScat, 256, 0, stream>>>(src, dst, dinv, h, agg);
    relu_k<<<gElem, 256, 0, stream>>>(agg, h, ent_out);
}

extern "C" void kernel_launch(void* const* d_in, const int* in_sizes, int n_in,
                              void* d_out, int out_size, void* d_ws, size_t ws_size,
                              hipStream_t stream) {
    const int* sr_seeds = (const int*)d_in[0];
    const int* tg_seeds = (const int*)d_in[1];
    const int* edges_sr = (const int*)d_in[2];
    const int* edges_tg = (const int*)d_in[3];
    const float* emb_sr = (const float*)d_in[4];
    const float* emb_tg = (const float*)d_in[5];
    const float* W0 = (const float*)d_in[6];
    const float* W1 = (const float*)d_in[7];
    float* out = (float*)d_out;

    // workspace layout (floats): dinv [100352] | h [12.8M] | agg [12.8M]  => ~98 MB
    float* dinv = (float*)d_ws;
    float* h = dinv + 100352;
    float* agg = h + (long long)NN * DIM;

    // output layout (floats): sr_seed | tg_seed | sr_ent | tg_ent
    float* sr_seed_out = out;
    float* tg_seed_out = out + (long long)NS * DIM;
    float* sr_ent = out + (long long)2 * NS * DIM;
    float* tg_ent = sr_ent + (long long)NN * DIM;

    run_graph(edges_sr, emb_sr, W0, W1, dinv, h, agg, sr_ent, stream);
    run_graph(edges_tg, emb_tg, W0, W1, dinv, h, agg, tg_ent, stream);

    const int gSeed = (int)(((long long)NS * 32 + 255) / 256);  // 1875
    gather_k<<<gSeed, 256, 0, stream>>>(sr_seeds, sr_ent, sr_seed_out);
    gather_k<<<gSeed, 256, 0, stream>>>(tg_seeds, tg_ent, tg_seed_out);
}

// Round 2
// 1354.667 us; speedup vs baseline: 8.4957x; 8.4957x over previous
//
#include <hip/hip_runtime.h>

#define NN 100000
#define NE 1600000
#define DIM 128
#define NS 15000
#define SCAN_BLOCKS ((NN + 255) / 256)  // 391

// ---------------- degree / CSR build ----------------
__global__ __launch_bounds__(256) void count_k(const int* __restrict__ dst, int* cnt) {
    int e = blockIdx.x * 256 + threadIdx.x;
    if (e < NE) atomicAdd(&cnt[dst[e]], 1);
}

__global__ __launch_bounds__(256) void dinv_k(const int* __restrict__ cnt, float* dinv) {
    int i = blockIdx.x * 256 + threadIdx.x;
    if (i < NN) dinv[i] = rsqrtf((float)(cnt[i] + 1));  // +1 self-loop
}

// scan phase A: per-block sums of cnt
__global__ __launch_bounds__(256) void scanA_k(const int* __restrict__ cnt, int* bsum) {
    __shared__ int s[256];
    const int t = threadIdx.x;
    const int i = blockIdx.x * 256 + t;
    s[t] = (i < NN) ? cnt[i] : 0;
    __syncthreads();
    for (int off = 128; off > 0; off >>= 1) {
        if (t < off) s[t] += s[t + off];
        __syncthreads();
    }
    if (t == 0) bsum[blockIdx.x] = s[0];
}

// scan phase B: exclusive scan of block sums (small: 391), set row_ptr[NN]
__global__ void scanB_k(int* bsum, int* row_ptr) {
    if (threadIdx.x == 0 && blockIdx.x == 0) {
        int run = 0;
        for (int b = 0; b < SCAN_BLOCKS; b++) {
            int x = bsum[b];
            bsum[b] = run;
            run += x;
        }
        row_ptr[NN] = run;  // == NE
    }
}

// scan phase C: per-block exclusive scan + block offset -> row_ptr, cursor
__global__ __launch_bounds__(256) void scanC_k(const int* __restrict__ cnt,
                                               const int* __restrict__ bsum,
                                               int* row_ptr, int* cursor) {
    __shared__ int s[256];
    const int t = threadIdx.x;
    const int i = blockIdx.x * 256 + t;
    const int v = (i < NN) ? cnt[i] : 0;
    s[t] = v;
    __syncthreads();
    for (int off = 1; off < 256; off <<= 1) {
        int add = (t >= off) ? s[t - off] : 0;
        __syncthreads();
        s[t] += add;
        __syncthreads();
    }
    if (i < NN) {
        const int rp = bsum[blockIdx.x] + s[t] - v;  // exclusive
        row_ptr[i] = rp;
        cursor[i] = rp;
    }
}

// fill: bucket edges by dst; precompute per-edge norm
__global__ __launch_bounds__(256) void fill_k(const int* __restrict__ src,
                                              const int* __restrict__ dst,
                                              const float* __restrict__ dinv,
                                              int* cursor,
                                              int* __restrict__ csr_src,
                                              float* __restrict__ csr_nrm) {
    int e = blockIdx.x * 256 + threadIdx.x;
    if (e >= NE) return;
    const int s = src[e];
    const int t = dst[e];
    const int pos = atomicAdd(&cursor[t], 1);
    csr_src[pos] = s;
    csr_nrm[pos] = dinv[s] * dinv[t];
}

// ---------------- dense transform: H = X @ W  (X:[N,128], W:[128,128]) ----------------
__global__ __launch_bounds__(256) void gemm_k(const float* __restrict__ X,
                                              const float* __restrict__ W,
                                              float* __restrict__ H) {
    __shared__ float xs[32 * DIM];
    const int tid = threadIdx.x;
    const long long row0 = (long long)blockIdx.x * 32;

    const float4* X4 = (const float4*)(X + row0 * DIM);
    float4* xs4 = (float4*)xs;
#pragma unroll
    for (int i = 0; i < 4; i++) xs4[tid + i * 256] = X4[tid + i * 256];
    __syncthreads();

    const int c = tid & 127;
    const int rbase = (tid >> 7) * 16;  // 0 or 16

    float acc[16];
#pragma unroll
    for (int r = 0; r < 16; r++) acc[r] = 0.f;

    for (int k = 0; k < DIM; k += 4) {
        const float w0 = W[(k + 0) * DIM + c];
        const float w1 = W[(k + 1) * DIM + c];
        const float w2 = W[(k + 2) * DIM + c];
        const float w3 = W[(k + 3) * DIM + c];
#pragma unroll
        for (int r = 0; r < 16; r++) {
            const float4 xv = *(const float4*)&xs[(rbase + r) * DIM + k];
            acc[r] += xv.x * w0 + xv.y * w1 + xv.z * w2 + xv.w * w3;
        }
    }
#pragma unroll
    for (int r = 0; r < 16; r++)
        H[(row0 + rbase + r) * DIM + c] = acc[r];
}

// ---------------- fused pull aggregation + self-loop + residual + ReLU ----------------
// One wave (64 lanes) per node; lane handles a float2 slice of DIM=128.
// out[t] = relu( (1+dinv^2)*h[t] + sum_e nrm[e]*h[csr_src[e]] )
__global__ __launch_bounds__(256) void pull_k(const int* __restrict__ row_ptr,
                                              const int* __restrict__ csr_src,
                                              const float* __restrict__ csr_nrm,
                                              const float* __restrict__ dinv,
                                              const float* __restrict__ H,
                                              float* __restrict__ out) {
    const int node = (int)(((long long)blockIdx.x * 256 + threadIdx.x) >> 6);
    if (node >= NN) return;
    const int lane = threadIdx.x & 63;
    const float2* __restrict__ H2 = (const float2*)H;

    const int beg = row_ptr[node];
    const int end = row_ptr[node + 1];
    const float d = dinv[node];
    const float sw = 1.0f + d * d;  // residual + self-loop weight

    const float2 hv = H2[(long long)node * 64 + lane];
    float ax = sw * hv.x;
    float ay = sw * hv.y;

    for (int base = beg; base < end; base += 64) {
        const int rem = end - base;
        int sl = 0;
        float nl = 0.f;
        if (lane < rem) {  // coalesced per-wave metadata load
            sl = csr_src[base + lane];
            nl = csr_nrm[base + lane];
        }
        const int iters = rem < 64 ? rem : 64;
        for (int j = 0; j < iters; ++j) {
            const int s = __shfl(sl, j);
            const float nrm = __shfl(nl, j);
            const float2 mv = H2[(long long)s * 64 + lane];
            ax += nrm * mv.x;
            ay += nrm * mv.y;
        }
    }
    float2 o;
    o.x = fmaxf(ax, 0.f);
    o.y = fmaxf(ay, 0.f);
    ((float2*)out)[(long long)node * 64 + lane] = o;
}

// ---------------- seed gather ----------------
__global__ __launch_bounds__(256) void gather_k(const int* __restrict__ seeds,
                                                const float* __restrict__ ent,
                                                float* __restrict__ out) {
    long long gid = (long long)blockIdx.x * 256 + threadIdx.x;
    const int s = (int)(gid >> 5);
    if (s >= NS) return;
    const int q = (int)(gid & 31);
    ((float4*)out)[(long long)s * 32 + q] =
        ((const float4*)ent)[(long long)seeds[s] * 32 + q];
}

// ---------------- per-graph driver (host) ----------------
static void run_graph(const int* edges, const float* emb, const float* W0, const float* W1,
                      int* cnt, float* dinv, int* row_ptr, int* cursor, int* bsum,
                      int* csr_src, float* csr_nrm, float* h,
                      float* ent_out, hipStream_t stream) {
    const int* src = edges;       // edges[0,:]
    const int* dst = edges + NE;  // edges[1,:]

    const int gE = (NE + 255) / 256;  // 6250
    const int gGemm = NN / 32;        // 3125
    const int gPull = (NN + 3) / 4;   // 25000 (4 waves/block, 1 node/wave)

    hipMemsetAsync(cnt, 0, NN * sizeof(int), stream);
    count_k<<<gE, 256, 0, stream>>>(dst, cnt);
    dinv_k<<<SCAN_BLOCKS, 256, 0, stream>>>(cnt, dinv);
    scanA_k<<<SCAN_BLOCKS, 256, 0, stream>>>(cnt, bsum);
    scanB_k<<<1, 64, 0, stream>>>(bsum, row_ptr);
    scanC_k<<<SCAN_BLOCKS, 256, 0, stream>>>(cnt, bsum, row_ptr, cursor);
    fill_k<<<gE, 256, 0, stream>>>(src, dst, dinv, cursor, csr_src, csr_nrm);

    // layer 1: x = emb -> x1 stored in ent_out (overwritten by layer 2)
    gemm_k<<<gGemm, 256, 0, stream>>>(emb, W0, h);
    pull_k<<<gPull, 256, 0, stream>>>(row_ptr, csr_src, csr_nrm, dinv, h, ent_out);

    // layer 2: x = x1 (in ent_out)
    gemm_k<<<gGemm, 256, 0, stream>>>(ent_out, W1, h);
    pull_k<<<gPull, 256, 0, stream>>>(row_ptr, csr_src, csr_nrm, dinv, h, ent_out);
}

extern "C" void kernel_launch(void* const* d_in, const int* in_sizes, int n_in,
                              void* d_out, int out_size, void* d_ws, size_t ws_size,
                              hipStream_t stream) {
    const int* sr_seeds = (const int*)d_in[0];
    const int* tg_seeds = (const int*)d_in[1];
    const int* edges_sr = (const int*)d_in[2];
    const int* edges_tg = (const int*)d_in[3];
    const float* emb_sr = (const float*)d_in[4];
    const float* emb_tg = (const float*)d_in[5];
    const float* W0 = (const float*)d_in[6];
    const float* W1 = (const float*)d_in[7];
    float* out = (float*)d_out;

    // workspace layout (4-byte units, 256-padded):
    // cnt[100352] dinv[100352] row_ptr[100352] cursor[100352] bsum[512]
    // csr_src[NE] csr_nrm[NE] h[NN*DIM]   => ~65.6 MB
    int* cnt = (int*)d_ws;
    float* dinv = (float*)(cnt + 100352);
    int* row_ptr = (int*)(dinv + 100352);
    int* cursor = row_ptr + 100352;
    int* bsum = cursor + 100352;
    int* csr_src = bsum + 512;
    float* csr_nrm = (float*)(csr_src + NE);
    float* h = csr_nrm + NE;

    // output layout (floats): sr_seed | tg_seed | sr_ent | tg_ent
    float* sr_seed_out = out;
    float* tg_seed_out = out + (long long)NS * DIM;
    float* sr_ent = out + (long long)2 * NS * DIM;
    float* tg_ent = sr_ent + (long long)NN * DIM;

    run_graph(edges_sr, emb_sr, W0, W1, cnt, dinv, row_ptr, cursor, bsum,
              csr_src, csr_nrm, h, sr_ent, stream);
    run_graph(edges_tg, emb_tg, W0, W1, cnt, dinv, row_ptr, cursor, bsum,
              csr_src, csr_nrm, h, tg_ent, stream);

    const int gSeed = (int)(((long long)NS * 32 + 255) / 256);  // 1875
    gather_k<<<gSeed, 256, 0, stream>>>(sr_seeds, sr_ent, sr_seed_out);
    gather_k<<<gSeed, 256, 0, stream>>>(tg_seeds, tg_ent, tg_seed_out);
}

// Round 3
// 1071.034 us; speedup vs baseline: 10.7456x; 1.2648x over previous
//
#include <hip/hip_runtime.h>

#define NN 100000
#define NE 1600000
#define DIM 128
#define NS 15000
#define SCAN_BLOCKS ((NN + 255) / 256)  // 391
#define PAD 136                         // LDS row stride in bf16 (272B = 17*16B, 2-way banks)

typedef __attribute__((ext_vector_type(8))) short frag_ab;  // 8 bf16
typedef __attribute__((ext_vector_type(4))) float frag_cd;  // 4 f32

__device__ __forceinline__ unsigned short f2bf(float f) {  // RNE
    unsigned int u = __float_as_uint(f);
    u += 0x7fff + ((u >> 16) & 1);
    return (unsigned short)(u >> 16);
}
__device__ __forceinline__ float bflo(unsigned int u) { return __uint_as_float(u << 16); }
__device__ __forceinline__ float bfhi(unsigned int u) { return __uint_as_float(u & 0xffff0000u); }

// ---------------- degree / CSR build ----------------
__global__ __launch_bounds__(256) void count_k(const int* __restrict__ dst, int* cnt) {
    int e = blockIdx.x * 256 + threadIdx.x;
    if (e < NE) atomicAdd(&cnt[dst[e]], 1);
}

__global__ __launch_bounds__(256) void dinv_k(const int* __restrict__ cnt, float* dinv) {
    int i = blockIdx.x * 256 + threadIdx.x;
    if (i < NN) dinv[i] = rsqrtf((float)(cnt[i] + 1));  // +1 self-loop
}

__global__ __launch_bounds__(256) void scanA_k(const int* __restrict__ cnt, int* bsum) {
    __shared__ int s[256];
    const int t = threadIdx.x;
    const int i = blockIdx.x * 256 + t;
    s[t] = (i < NN) ? cnt[i] : 0;
    __syncthreads();
    for (int off = 128; off > 0; off >>= 1) {
        if (t < off) s[t] += s[t + off];
        __syncthreads();
    }
    if (t == 0) bsum[blockIdx.x] = s[0];
}

// parallel exclusive scan of 391 block sums (was serial: ~391 dependent loads)
__global__ __launch_bounds__(512) void scanB_k(int* bsum, int* row_ptr) {
    __shared__ int s[512];
    const int t = threadIdx.x;
    const int v = (t < SCAN_BLOCKS) ? bsum[t] : 0;
    s[t] = v;
    __syncthreads();
    for (int off = 1; off < 512; off <<= 1) {
        int add = (t >= off) ? s[t - off] : 0;
        __syncthreads();
        s[t] += add;
        __syncthreads();
    }
    if (t < SCAN_BLOCKS) bsum[t] = s[t] - v;           // exclusive
    if (t == SCAN_BLOCKS - 1) row_ptr[NN] = s[t];      // == NE
}

__global__ __launch_bounds__(256) void scanC_k(const int* __restrict__ cnt,
                                               const int* __restrict__ bsum,
                                               int* row_ptr, int* cursor) {
    __shared__ int s[256];
    const int t = threadIdx.x;
    const int i = blockIdx.x * 256 + t;
    const int v = (i < NN) ? cnt[i] : 0;
    s[t] = v;
    __syncthreads();
    for (int off = 1; off < 256; off <<= 1) {
        int add = (t >= off) ? s[t - off] : 0;
        __syncthreads();
        s[t] += add;
        __syncthreads();
    }
    if (i < NN) {
        const int rp = bsum[blockIdx.x] + s[t] - v;
        row_ptr[i] = rp;
        cursor[i] = rp;
    }
}

__global__ __launch_bounds__(256) void fill_k(const int* __restrict__ src,
                                              const int* __restrict__ dst,
                                              const float* __restrict__ dinv,
                                              int* cursor,
                                              int* __restrict__ csr_src,
                                              float* __restrict__ csr_nrm) {
    int e = blockIdx.x * 256 + threadIdx.x;
    if (e >= NE) return;
    const int s = src[e];
    const int t = dst[e];
    const int pos = atomicAdd(&cursor[t], 1);
    csr_src[pos] = s;
    csr_nrm[pos] = dinv[s] * dinv[t];
}

// ---------------- fp32 -> bf16 conversions ----------------
__global__ __launch_bounds__(256) void convX_k(const float* __restrict__ x,
                                               unsigned short* __restrict__ xb) {
    long long i = (long long)blockIdx.x * 256 + threadIdx.x;  // over NN*32 float4s
    if (i >= (long long)NN * 32) return;
    float4 v = ((const float4*)x)[i];
    ushort4 o;
    o.x = f2bf(v.x); o.y = f2bf(v.y); o.z = f2bf(v.z); o.w = f2bf(v.w);
    ((ushort4*)xb)[i] = o;
}

// Wt[n][k] = bf16(W[k][n])  (transposed for MFMA B-fragment b128 reads)
__global__ __launch_bounds__(256) void convW_k(const float* __restrict__ W,
                                               unsigned short* __restrict__ wt) {
    int i = blockIdx.x * 256 + threadIdx.x;  // 16384
    if (i >= DIM * DIM) return;
    const int n = i & 127, k = i >> 7;
    wt[n * DIM + k] = f2bf(W[k * DIM + n]);
}

// ---------------- MFMA GEMM: Hb = Xb @ W  (bf16 in, bf16 out, fp32 acc) ----------------
// block = 256 (4 waves), 64 rows/block; wave handles 16 rows x 128 cols.
__global__ __launch_bounds__(256) void gemm_mfma_k(const unsigned short* __restrict__ Xb,
                                                   const unsigned short* __restrict__ Wt,
                                                   unsigned short* __restrict__ Hb) {
    __shared__ unsigned short xs[64 * PAD];   // 17.4 KB
    __shared__ unsigned short ws[128 * PAD];  // 34.8 KB
    const int tid = threadIdx.x;
    const int row0 = blockIdx.x * 64;

    // stage Wt: 128 rows x 16 octets of 8 bf16
    for (int i = tid; i < 128 * 16; i += 256) {
        const int r = i >> 4, o = i & 15;
        *(uint4*)&ws[r * PAD + o * 8] = *(const uint4*)&Wt[r * DIM + o * 8];
    }
    // stage X: 64 rows x 16 octets (clamp OOB rows)
    for (int i = tid; i < 64 * 16; i += 256) {
        const int r = i >> 4, o = i & 15;
        int gr = row0 + r; if (gr >= NN) gr = NN - 1;
        *(uint4*)&xs[r * PAD + o * 8] = *(const uint4*)&Xb[(long long)gr * DIM + o * 8];
    }
    __syncthreads();

    const int wave = tid >> 6;
    const int lane = tid & 63;
    const int m = lane & 15;
    const int quad = lane >> 4;
    const int rbase = wave * 16;

    frag_cd acc[8];
#pragma unroll
    for (int ct = 0; ct < 8; ct++) acc[ct] = (frag_cd){0.f, 0.f, 0.f, 0.f};

#pragma unroll
    for (int ks = 0; ks < 4; ks++) {
        const frag_ab a = *(const frag_ab*)&xs[(rbase + m) * PAD + ks * 32 + quad * 8];
#pragma unroll
        for (int ct = 0; ct < 8; ct++) {
            const frag_ab b = *(const frag_ab*)&ws[(ct * 16 + m) * PAD + ks * 32 + quad * 8];
            acc[ct] = __builtin_amdgcn_mfma_f32_16x16x32_bf16(a, b, acc[ct], 0, 0, 0);
        }
    }

    // C/D layout: col = lane&15, row = quad*4 + reg
#pragma unroll
    for (int ct = 0; ct < 8; ct++) {
#pragma unroll
        for (int r = 0; r < 4; r++) {
            const int grow = row0 + rbase + quad * 4 + r;
            if (grow < NN) Hb[(long long)grow * DIM + ct * 16 + m] = f2bf(acc[ct][r]);
        }
    }
}

// ---------------- fused pull + self-loop + residual + ReLU (bf16 messages) ----------------
// One wave per node; lane handles 2 channels (one dword of bf16x2 per gather).
template <bool OUT_BF16>
__global__ __launch_bounds__(256) void pull_k(const int* __restrict__ row_ptr,
                                              const int* __restrict__ csr_src,
                                              const float* __restrict__ csr_nrm,
                                              const float* __restrict__ dinv,
                                              const unsigned short* __restrict__ Hb,
                                              float* __restrict__ outf,
                                              unsigned short* __restrict__ outb) {
    const int node = (int)(((long long)blockIdx.x * 256 + threadIdx.x) >> 6);
    if (node >= NN) return;
    const int lane = threadIdx.x & 63;
    const unsigned int* __restrict__ H2 = (const unsigned int*)Hb;

    const int beg = row_ptr[node];
    const int end = row_ptr[node + 1];
    const float d = dinv[node];
    const float sw = 1.0f + d * d;  // residual + self-loop weight

    const unsigned int hu = H2[(long long)node * 64 + lane];
    float ax = sw * bflo(hu);
    float ay = sw * bfhi(hu);

    for (int base = beg; base < end; base += 64) {
        const int rem = end - base;
        int sl = 0;
        float nl = 0.f;
        if (lane < rem) {
            sl = csr_src[base + lane];
            nl = csr_nrm[base + lane];
        }
        const int iters = rem < 64 ? rem : 64;
        for (int j = 0; j < iters; ++j) {
            const int s = __shfl(sl, j);
            const float nrm = __shfl(nl, j);
            const unsigned int mu = H2[(long long)s * 64 + lane];
            ax += nrm * bflo(mu);
            ay += nrm * bfhi(mu);
        }
    }
    ax = fmaxf(ax, 0.f);
    ay = fmaxf(ay, 0.f);
    if (OUT_BF16) {
        ((unsigned int*)outb)[(long long)node * 64 + lane] =
            (unsigned int)f2bf(ax) | ((unsigned int)f2bf(ay) << 16);
    } else {
        float2 o; o.x = ax; o.y = ay;
        ((float2*)outf)[(long long)node * 64 + lane] = o;
    }
}

// ---------------- seed gather ----------------
__global__ __launch_bounds__(256) void gather_k(const int* __restrict__ seeds,
                                                const float* __restrict__ ent,
                                                float* __restrict__ out) {
    long long gid = (long long)blockIdx.x * 256 + threadIdx.x;
    const int s = (int)(gid >> 5);
    if (s >= NS) return;
    const int q = (int)(gid & 31);
    ((float4*)out)[(long long)s * 32 + q] =
        ((const float4*)ent)[(long long)seeds[s] * 32 + q];
}

// ---------------- per-graph driver (host) ----------------
static void run_graph(const int* edges, const float* emb,
                      const unsigned short* wt0, const unsigned short* wt1,
                      int* cnt, float* dinv, int* row_ptr, int* cursor, int* bsum,
                      int* csr_src, float* csr_nrm,
                      unsigned short* xb, unsigned short* hb,
                      float* ent_out, hipStream_t stream) {
    const int* src = edges;
    const int* dst = edges + NE;

    const int gE = (NE + 255) / 256;        // 6250
    const int gGemm = (NN + 63) / 64;       // 1563
    const int gPull = (NN + 3) / 4;         // 25000
    const int gElem = (NN * 32 + 255) / 256;

    hipMemsetAsync(cnt, 0, NN * sizeof(int), stream);
    count_k<<<gE, 256, 0, stream>>>(dst, cnt);
    dinv_k<<<SCAN_BLOCKS, 256, 0, stream>>>(cnt, dinv);
    scanA_k<<<SCAN_BLOCKS, 256, 0, stream>>>(cnt, bsum);
    scanB_k<<<1, 512, 0, stream>>>(bsum, row_ptr);
    scanC_k<<<SCAN_BLOCKS, 256, 0, stream>>>(cnt, bsum, row_ptr, cursor);
    fill_k<<<gE, 256, 0, stream>>>(src, dst, dinv, cursor, csr_src, csr_nrm);

    convX_k<<<gElem, 256, 0, stream>>>(emb, xb);

    // layer 1
    gemm_mfma_k<<<gGemm, 256, 0, stream>>>(xb, wt0, hb);
    pull_k<true><<<gPull, 256, 0, stream>>>(row_ptr, csr_src, csr_nrm, dinv, hb,
                                            nullptr, xb);  // x1 (bf16) -> xb
    // layer 2
    gemm_mfma_k<<<gGemm, 256, 0, stream>>>(xb, wt1, hb);
    pull_k<false><<<gPull, 256, 0, stream>>>(row_ptr, csr_src, csr_nrm, dinv, hb,
                                             ent_out, nullptr);
}

extern "C" void kernel_launch(void* const* d_in, const int* in_sizes, int n_in,
                              void* d_out, int out_size, void* d_ws, size_t ws_size,
                              hipStream_t stream) {
    const int* sr_seeds = (const int*)d_in[0];
    const int* tg_seeds = (const int*)d_in[1];
    const int* edges_sr = (const int*)d_in[2];
    const int* edges_tg = (const int*)d_in[3];
    const float* emb_sr = (const float*)d_in[4];
    const float* emb_tg = (const float*)d_in[5];
    const float* W0 = (const float*)d_in[6];
    const float* W1 = (const float*)d_in[7];
    float* out = (float*)d_out;

    // ws layout (4B units): cnt dinv row_ptr cursor [100352 each] bsum[512]
    // csr_src[NE] csr_nrm[NE] | wt0 wt1 [16384 ushort] xb hb [NN*DIM ushort] ~ 66 MB
    int* cnt = (int*)d_ws;
    float* dinv = (float*)(cnt + 100352);
    int* row_ptr = (int*)(dinv + 100352);
    int* cursor = row_ptr + 100352;
    int* bsum = cursor + 100352;
    int* csr_src = bsum + 512;
    float* csr_nrm = (float*)(csr_src + NE);
    unsigned short* wt0 = (unsigned short*)(csr_nrm + NE);
    unsigned short* wt1 = wt0 + DIM * DIM;
    unsigned short* xb = wt1 + DIM * DIM;
    unsigned short* hb = xb + (long long)NN * DIM;

    float* sr_seed_out = out;
    float* tg_seed_out = out + (long long)NS * DIM;
    float* sr_ent = out + (long long)2 * NS * DIM;
    float* tg_ent = sr_ent + (long long)NN * DIM;

    convW_k<<<(DIM * DIM + 255) / 256, 256, 0, stream>>>(W0, wt0);
    convW_k<<<(DIM * DIM + 255) / 256, 256, 0, stream>>>(W1, wt1);

    run_graph(edges_sr, emb_sr, wt0, wt1, cnt, dinv, row_ptr, cursor, bsum,
              csr_src, csr_nrm, xb, hb, sr_ent, stream);
    run_graph(edges_tg, emb_tg, wt0, wt1, cnt, dinv, row_ptr, cursor, bsum,
              csr_src, csr_nrm, xb, hb, tg_ent, stream);

    const int gSeed = (int)(((long long)NS * 32 + 255) / 256);
    gather_k<<<gSeed, 256, 0, stream>>>(sr_seeds, sr_ent, sr_seed_out);
    gather_k<<<gSeed, 256, 0, stream>>>(tg_seeds, tg_ent, tg_seed_out);
}

// Round 5
// 905.675 us; speedup vs baseline: 12.7075x; 1.1826x over previous
//
#include <hip/hip_runtime.h>

#define NN 100000
#define NE 1600000
#define NT (2 * NN)        // combined nodes (sr | tg+NN)
#define ET (2 * NE)        // combined edges
#define DIM 128
#define NS 15000
#define SB2 ((NT + 255) / 256)  // 782 scan blocks
#define PAD 136                 // LDS row stride in bf16

typedef __attribute__((ext_vector_type(8))) short frag_ab;  // 8 bf16
typedef __attribute__((ext_vector_type(4))) float frag_cd;  // 4 f32

__device__ __forceinline__ unsigned short f2bf(float f) {  // RNE
    unsigned int u = __float_as_uint(f);
    u += 0x7fff + ((u >> 16) & 1);
    return (unsigned short)(u >> 16);
}
__device__ __forceinline__ float bflo(unsigned int u) { return __uint_as_float(u << 16); }
__device__ __forceinline__ float bfhi(unsigned int u) { return __uint_as_float(u & 0xffff0000u); }

// ---------------- degree (both graphs in one pass) ----------------
__global__ __launch_bounds__(256) void count_k(const int* __restrict__ e_sr,
                                               const int* __restrict__ e_tg, int* cnt) {
    int e = blockIdx.x * 256 + threadIdx.x;
    if (e >= ET) return;
    int t;
    if (e < NE) t = e_sr[NE + e];            // dst_sr
    else        t = e_tg[e] + NN;            // dst_tg
    atomicAdd(&cnt[t], 1);
}

__global__ __launch_bounds__(256) void dinv_k(const int* __restrict__ cnt, float* dinv) {
    int i = blockIdx.x * 256 + threadIdx.x;
    if (i < NT) dinv[i] = rsqrtf((float)(cnt[i] + 1));  // +1 self-loop
}

// ---------------- scan: row_ptr = exclusive_scan(cnt) ----------------
__global__ __launch_bounds__(256) void scanA_k(const int* __restrict__ cnt, int* bsum) {
    __shared__ int s[256];
    const int t = threadIdx.x;
    const int i = blockIdx.x * 256 + t;
    s[t] = (i < NT) ? cnt[i] : 0;
    __syncthreads();
    for (int off = 128; off > 0; off >>= 1) {
        if (t < off) s[t] += s[t + off];
        __syncthreads();
    }
    if (t == 0) bsum[blockIdx.x] = s[0];
}

__global__ __launch_bounds__(1024) void scanB_k(int* bsum, int* row_ptr) {
    __shared__ int s[1024];
    const int t = threadIdx.x;
    const int v = (t < SB2) ? bsum[t] : 0;
    s[t] = v;
    __syncthreads();
    for (int off = 1; off < 1024; off <<= 1) {
        int add = (t >= off) ? s[t - off] : 0;
        __syncthreads();
        s[t] += add;
        __syncthreads();
    }
    if (t < SB2) bsum[t] = s[t] - v;        // exclusive
    if (t == SB2 - 1) row_ptr[NT] = s[t];   // == ET
}

// writes row_ptr; reuses cnt's storage as the fill cursor (cnt dead after)
__global__ __launch_bounds__(256) void scanC_k(int* cnt_cursor,
                                               const int* __restrict__ bsum,
                                               int* row_ptr) {
    __shared__ int s[256];
    const int t = threadIdx.x;
    const int i = blockIdx.x * 256 + t;
    const int v = (i < NT) ? cnt_cursor[i] : 0;
    s[t] = v;
    __syncthreads();
    for (int off = 1; off < 256; off <<= 1) {
        int add = (t >= off) ? s[t - off] : 0;
        __syncthreads();
        s[t] += add;
        __syncthreads();
    }
    if (i < NT) {
        const int rp = bsum[blockIdx.x] + s[t] - v;
        row_ptr[i] = rp;
        cnt_cursor[i] = rp;  // same index this thread read; safe aliasing
    }
}

// ---------------- fill: one 4B scattered store per edge ----------------
__global__ __launch_bounds__(256) void fill_k(const int* __restrict__ e_sr,
                                              const int* __restrict__ e_tg,
                                              int* cursor, int* __restrict__ csr_src) {
    int e = blockIdx.x * 256 + threadIdx.x;
    if (e >= ET) return;
    int s, t;
    if (e < NE) { s = e_sr[e];           t = e_sr[NE + e]; }
    else        { s = e_tg[e - NE] + NN; t = e_tg[e] + NN; }
    const int pos = atomicAdd(&cursor[t], 1);
    csr_src[pos] = s;
}

// ---------------- fp32 -> bf16 conversion (both embeddings) ----------------
__global__ __launch_bounds__(256) void convX_k(const float* __restrict__ emb_sr,
                                               const float* __restrict__ emb_tg,
                                               unsigned short* __restrict__ xb) {
    const int i = blockIdx.x * 256 + threadIdx.x;  // over NT*32 float4s
    if (i >= NT * 32) return;
    const int node = i >> 5;
    float4 v = (node < NN) ? ((const float4*)emb_sr)[i]
                           : ((const float4*)emb_tg)[i - NN * 32];
    ushort4 o;
    o.x = f2bf(v.x); o.y = f2bf(v.y); o.z = f2bf(v.z); o.w = f2bf(v.w);
    ((ushort4*)xb)[i] = o;
}

// Wt[n][k] = bf16(W[k][n])
__global__ __launch_bounds__(256) void convW_k(const float* __restrict__ W,
                                               unsigned short* __restrict__ wt) {
    int i = blockIdx.x * 256 + threadIdx.x;
    if (i >= DIM * DIM) return;
    const int n = i & 127, k = i >> 7;
    wt[n * DIM + k] = f2bf(W[k * DIM + n]);
}

// ---------------- MFMA GEMM + dinv scaling: Gb = dinv ⊙ (Xb @ W) ----------------
__global__ __launch_bounds__(256) void gemm_mfma_k(const unsigned short* __restrict__ Xb,
                                                   const unsigned short* __restrict__ Wt,
                                                   const float* __restrict__ dinv,
                                                   unsigned short* __restrict__ Gb) {
    __shared__ unsigned short xs[64 * PAD];   // 17.4 KB
    __shared__ unsigned short ws[128 * PAD];  // 34.8 KB
    const int tid = threadIdx.x;
    const int row0 = blockIdx.x * 64;

    for (int i = tid; i < 128 * 16; i += 256) {
        const int r = i >> 4, o = i & 15;
        *(uint4*)&ws[r * PAD + o * 8] = *(const uint4*)&Wt[r * DIM + o * 8];
    }
    for (int i = tid; i < 64 * 16; i += 256) {
        const int r = i >> 4, o = i & 15;
        int gr = row0 + r; if (gr >= NT) gr = NT - 1;
        *(uint4*)&xs[r * PAD + o * 8] = *(const uint4*)&Xb[gr * DIM + o * 8];
    }
    __syncthreads();

    const int wave = tid >> 6;
    const int lane = tid & 63;
    const int m = lane & 15;
    const int quad = lane >> 4;
    const int rbase = wave * 16;

    frag_cd acc[8];
#pragma unroll
    for (int ct = 0; ct < 8; ct++) acc[ct] = (frag_cd){0.f, 0.f, 0.f, 0.f};

#pragma unroll
    for (int ks = 0; ks < 4; ks++) {
        const frag_ab a = *(const frag_ab*)&xs[(rbase + m) * PAD + ks * 32 + quad * 8];
#pragma unroll
        for (int ct = 0; ct < 8; ct++) {
            const frag_ab b = *(const frag_ab*)&ws[(ct * 16 + m) * PAD + ks * 32 + quad * 8];
            acc[ct] = __builtin_amdgcn_mfma_f32_16x16x32_bf16(a, b, acc[ct], 0, 0, 0);
        }
    }

    // C/D layout: col = lane&15, row = quad*4 + reg
#pragma unroll
    for (int r = 0; r < 4; r++) {
        const int grow = row0 + rbase + quad * 4 + r;
        if (grow < NT) {
            const float dv = dinv[grow];
#pragma unroll
            for (int ct = 0; ct < 8; ct++)
                Gb[grow * DIM + ct * 16 + m] = f2bf(dv * acc[ct][r]);
        }
    }
}

// ---------------- fused pull (weightless gather) + residual + ReLU ----------------
// out[t] = relu( dinv[t]*(g[t] + Σ g[src]) + g[t]*sqrt(deg[t]) )
template <bool OUT_BF16>
__global__ __launch_bounds__(256) void pull_k(const int* __restrict__ row_ptr,
                                              const int* __restrict__ csr_src,
                                              const float* __restrict__ dinv,
                                              const unsigned short* __restrict__ Gb,
                                              float* __restrict__ outf,
                                              unsigned short* __restrict__ outb) {
    const int node = (blockIdx.x * 256 + threadIdx.x) >> 6;
    if (node >= NT) return;
    const int lane = threadIdx.x & 63;
    const unsigned int* __restrict__ G2 = (const unsigned int*)Gb;

    const int beg = row_ptr[node];
    const int end = row_ptr[node + 1];
    const float d = dinv[node];
    const float sq = 1.0f / d;  // sqrt(deg)

    const unsigned int gu = G2[node * 64 + lane];
    float sx = bflo(gu);  // self-loop term g[t]
    float sy = bfhi(gu);
    const float hx = sx * sq;  // residual h[t] = g[t]*sqrt(deg)
    const float hy = sy * sq;

    for (int base = beg; base < end; base += 64) {
        int rem = end - base; if (rem > 64) rem = 64;
        const int sl = (lane < rem) ? csr_src[base + lane] : 0;
        int j = 0;
        for (; j + 4 <= rem; j += 4) {
            const int s0 = __shfl(sl, j + 0);
            const int s1 = __shfl(sl, j + 1);
            const int s2 = __shfl(sl, j + 2);
            const int s3 = __shfl(sl, j + 3);
            const unsigned int m0 = G2[s0 * 64 + lane];
            const unsigned int m1 = G2[s1 * 64 + lane];
            const unsigned int m2 = G2[s2 * 64 + lane];
            const unsigned int m3 = G2[s3 * 64 + lane];
            sx += bflo(m0) + bflo(m1) + bflo(m2) + bflo(m3);
            sy += bfhi(m0) + bfhi(m1) + bfhi(m2) + bfhi(m3);
        }
        for (; j < rem; ++j) {
            const int s = __shfl(sl, j);
            const unsigned int mu = G2[s * 64 + lane];
            sx += bflo(mu);
            sy += bfhi(mu);
        }
    }
    const float ax = fmaxf(d * sx + hx, 0.f);
    const float ay = fmaxf(d * sy + hy, 0.f);
    if (OUT_BF16) {
        ((unsigned int*)outb)[node * 64 + lane] =
            (unsigned int)f2bf(ax) | ((unsigned int)f2bf(ay) << 16);
    } else {
        float2 o; o.x = ax; o.y = ay;
        ((float2*)outf)[node * 64 + lane] = o;
    }
}

// ---------------- seed gather ----------------
__global__ __launch_bounds__(256) void gather_k(const int* __restrict__ seeds,
                                                const float* __restrict__ ent,
                                                float* __restrict__ out, int node_off) {
    const int gid = blockIdx.x * 256 + threadIdx.x;
    const int s = gid >> 5;
    if (s >= NS) return;
    const int q = gid & 31;
    ((float4*)out)[s * 32 + q] =
        ((const float4*)ent)[(seeds[s] + node_off) * 32 + q];
}

extern "C" void kernel_launch(void* const* d_in, const int* in_sizes, int n_in,
                              void* d_out, int out_size, void* d_ws, size_t ws_size,
                              hipStream_t stream) {
    const int* sr_seeds = (const int*)d_in[0];
    const int* tg_seeds = (const int*)d_in[1];
    const int* edges_sr = (const int*)d_in[2];
    const int* edges_tg = (const int*)d_in[3];
    const float* emb_sr = (const float*)d_in[4];
    const float* emb_tg = (const float*)d_in[5];
    const float* W0 = (const float*)d_in[6];
    const float* W1 = (const float*)d_in[7];
    float* out = (float*)d_out;

    // ws layout (4B words): cnt/cursor[200704] dinv[200704] row_ptr[200704]
    // bsum[1024] csr_src[ET] wt0+wt1[16384 words] hb[NT*DIM ushort]
    // total = 16,619,520 words = 66.5 MB  (R3-proven footprint; R4's 119 MB overflowed ws)
    int* cnt = (int*)d_ws;  // doubles as fill cursor after scanC
    float* dinv = (float*)(cnt + 200704);
    int* row_ptr = (int*)(dinv + 200704);
    int* bsum = row_ptr + 200704;
    int* csr_src = bsum + 1024;
    unsigned short* wt0 = (unsigned short*)(csr_src + ET);
    unsigned short* wt1 = wt0 + DIM * DIM;
    unsigned short* hb = wt1 + DIM * DIM;  // [NT*DIM] bf16

    // output layout (floats): sr_seed | tg_seed | ent [NT, DIM]
    float* sr_seed_out = out;
    float* tg_seed_out = out + (long long)NS * DIM;
    float* ent = out + (long long)2 * NS * DIM;
    // x1 (bf16) borrows the ent region: consumed by layer-2 gemm before
    // pull<false> overwrites the region with the final f32 ent.
    unsigned short* xb = (unsigned short*)ent;

    const int gE = (ET + 255) / 256;       // 12500
    const int gGemm = (NT + 63) / 64;      // 3125
    const int gPull = NT / 4;              // 50000
    const int gElem = (NT * 32 + 255) / 256;

    convW_k<<<(DIM * DIM + 255) / 256, 256, 0, stream>>>(W0, wt0);
    convW_k<<<(DIM * DIM + 255) / 256, 256, 0, stream>>>(W1, wt1);

    hipMemsetAsync(cnt, 0, NT * sizeof(int), stream);
    count_k<<<gE, 256, 0, stream>>>(edges_sr, edges_tg, cnt);
    dinv_k<<<SB2, 256, 0, stream>>>(cnt, dinv);
    scanA_k<<<SB2, 256, 0, stream>>>(cnt, bsum);
    scanB_k<<<1, 1024, 0, stream>>>(bsum, row_ptr);
    scanC_k<<<SB2, 256, 0, stream>>>(cnt, bsum, row_ptr);
    fill_k<<<gE, 256, 0, stream>>>(edges_sr, edges_tg, cnt, csr_src);

    convX_k<<<gElem, 256, 0, stream>>>(emb_sr, emb_tg, xb);  // x0 -> xb (ent region)

    // layer 1: g = dinv ⊙ (x0@W0) -> hb ; x1(bf16) -> xb
    gemm_mfma_k<<<gGemm, 256, 0, stream>>>(xb, wt0, dinv, hb);
    pull_k<true><<<gPull, 256, 0, stream>>>(row_ptr, csr_src, dinv, hb, nullptr, xb);
    // layer 2: g = dinv ⊙ (x1@W1) -> hb ; ent(f32) overwrites xb's region
    gemm_mfma_k<<<gGemm, 256, 0, stream>>>(xb, wt1, dinv, hb);
    pull_k<false><<<gPull, 256, 0, stream>>>(row_ptr, csr_src, dinv, hb, ent, nullptr);

    const int gSeed = (NS * 32 + 255) / 256;
    gather_k<<<gSeed, 256, 0, stream>>>(sr_seeds, ent, sr_seed_out, 0);
    gather_k<<<gSeed, 256, 0, stream>>>(tg_seeds, ent, tg_seed_out, NN);
}